// Round 11
// baseline (632.554 us; speedup 1.0000x reference)
//
#include <hip/hip_runtime.h>

#define NSHOTS 4
#define NT     512
#define NZ     256
#define NX     256
#define NRECS  128

static constexpr float DTf    = 0.001f;
static constexpr float INVDH2 = 1.0f / (10.0f * 10.0f);

#define K      8                  // steps per phase
#define TZ     16                 // interior z rows per tile
#define XI     48                 // interior x columns per tile
#define HX     8                  // x halo lanes each side (== K)
#define EXTZ   32                 // window rows = TZ + 2K (all in registers)
#define NPRW   16                 // v2f row-pairs per thread
#define NTZ    (NZ/TZ)            // 16
#define NTX    6                  // x tiles at x0 = 0,48,...,240 (ragged last)
#define NTILES (NSHOTS*NTZ*NTX)   // 384 autonomous waves
#define NPH    (NT/K)             // 64

typedef float v2f __attribute__((ext_vector_type(2)));
typedef unsigned long long ull;

// lane i <- lane i-1 (left x-neighbor); OOB lane 0 reads 0 (bound_ctrl=1)
__device__ __forceinline__ float nbr_left(float v) {
  return __int_as_float(__builtin_amdgcn_update_dpp(
      0, __float_as_int(v), 0x138 /*WAVE_SHR1*/, 0xf, 0xf, true));
}
// lane i <- lane i+1 (right x-neighbor); OOB lane 63 reads 0
__device__ __forceinline__ float nbr_right(float v) {
  return __int_as_float(__builtin_amdgcn_update_dpp(
      0, __float_as_int(v), 0x130 /*WAVE_SHL1*/, 0xf, 0xf, true));
}

// LLC-coherent (cross-XCD) 8B access: agent-scope relaxed -> sc0 sc1.
__device__ __forceinline__ ull pload(const ull* p) {
  return __hip_atomic_load(p, __ATOMIC_RELAXED, __HIP_MEMORY_SCOPE_AGENT);
}
__device__ __forceinline__ void pstore(ull* p, ull v) {
  __hip_atomic_store(p, v, __ATOMIC_RELAXED, __HIP_MEMORY_SCOPE_AGENT);
}

// pack (cur, prev) into one self-tagged 8B word: low 2 bits of prev's
// mantissa carry the phase tag (<= 3 ulp perturbation of halo prev only)
__device__ __forceinline__ ull pack_w(float cur, float prev, unsigned tg) {
  const unsigned hi = (__float_as_uint(prev) & ~3u) | tg;
  return ((ull)hi << 32) | (ull)__float_as_uint(cur);
}
__device__ __forceinline__ float w_cur(ull w)  { return __uint_as_float((unsigned)w); }
__device__ __forceinline__ float w_prev(ull w) {
  return __uint_as_float(((unsigned)(w >> 32)) & ~3u);
}
// per-buffer tag cycles 1,2,3 (phase q uses buffer q&1): never 0 (= memset)
__device__ __forceinline__ unsigned tag_of(int q) {
  return ((unsigned)(q >> 1) % 3u) + 1u;
}

__global__ __launch_bounds__(64, 1) void wave_pk(
    ull* __restrict__ gA, ull* __restrict__ gB,         // tagged (cur,prev) buffers
    const float* __restrict__ vp, const float* __restrict__ xwav,
    const int* __restrict__ src_z, const int* __restrict__ src_x,
    const int* __restrict__ rec_z, const int* __restrict__ rec_x,
    float* __restrict__ out)                            // [NSHOTS*NT*NRECS]
{
  const int bid  = blockIdx.x;          // one autonomous wave per block
  const int s    = bid / (NTZ * NTX);
  const int rem  = bid - s * (NTZ * NTX);
  const int tz   = rem / NTX;
  const int tx   = rem - tz * NTX;
  const int lane = threadIdx.x;

  const int gz0 = tz * TZ - K;          // window origin (z), rows 0..31
  const int gx0 = tx * XI - HX;         // window origin (x), lanes 0..63
  const int gx  = gx0 + lane;
  const bool xok = (unsigned)gx < (unsigned)NX;
  const int off0 = (s * NZ + gz0) * NX + gx;   // row i -> off0 + i*NX

  // per-window-row in-domain bits
  unsigned okBits = 0;
  if (xok) {
    #pragma unroll
    for (int i = 0; i < EXTZ; ++i)
      if ((unsigned)(gz0 + i) < (unsigned)NZ) okBits |= 1u << i;
  }

  // interior (owner/writeback) lanes: window x-interior AND in-domain
  const bool wbLane = (lane >= HX) && (lane < HX + XI) && xok;
  const unsigned keepM = wbLane ? 0x00FFFF00u : 0u;   // rows 8..23 kept

  // coefficients; out-of-domain cells get c2=0 -> p'=2p-prev keeps them 0
  v2f c22[NPRW], a2[NPRW], b2[NPRW];
  #pragma unroll
  for (int p = 0; p < NPRW; ++p) {
    #pragma unroll
    for (int h = 0; h < 2; ++h) {
      const int i = 2 * p + h;
      float v = ((okBits >> i) & 1) ? vp[(gz0 + i) * NX + gx] : 0.0f;
      v *= DTf;
      const float c2 = v * v * INVDH2;
      if (h == 0) c22[p].x = c2; else c22[p].y = c2;
    }
    a2[p] = (v2f)(0.0f); b2[p] = (v2f)(0.0f);
  }

  // source: window coords; inject redundantly in every window containing it
  const int wz = src_z[s] - gz0;        // window row of source
  const int wl = src_x[s] - gx0;        // window lane of source
  const bool hasSrc = ((unsigned)wz < (unsigned)EXTZ) && ((unsigned)wl < 64u);
  const bool srcLane = (wl == lane);

  // receiver ownership (unique: tiles partition the domain by interior).
  // 2 packed fast slots + overflow bitmask per thread.
  unsigned e0 = 0, e1 = 0, ov[4] = {0, 0, 0, 0};
  {
    int cnt = 0;
    #pragma unroll 1
    for (int r = 0; r < NRECS; ++r) {
      const int er = rec_z[s * NRECS + r] - tz * TZ;   // 0..15 if mine (z)
      const int ex = rec_x[s * NRECS + r] - tx * XI;   // 0..47 if mine (x)
      if ((unsigned)er < (unsigned)TZ && (unsigned)ex < (unsigned)XI &&
          ex + HX == lane) {
        const unsigned e = 0x8000u | ((unsigned)(er + K) << 8) | (unsigned)r;
        if (cnt == 0) e0 = e;
        else if (cnt == 1) e1 = e;
        else ov[r >> 5] |= 1u << (r & 31);
        ++cnt;
      }
    }
  }
  const bool hasOvf = (ov[0] | ov[1] | ov[2] | ov[3]) != 0;

  float amp[K];

  // select interior value at window row wr (8..23) from pairs 4..11
  auto selRow = [](const v2f (&n)[NPRW], int wr) -> float {
    const int q2 = (wr >> 1) - 4;                     // 0..7
    const v2f m01 = (q2 & 1) ? n[5]  : n[4];
    const v2f m23 = (q2 & 1) ? n[7]  : n[6];
    const v2f m45 = (q2 & 1) ? n[9]  : n[8];
    const v2f m67 = (q2 & 1) ? n[11] : n[10];
    const v2f ma  = (q2 & 2) ? m23 : m01;
    const v2f mb  = (q2 & 2) ? m67 : m45;
    const v2f mf  = (q2 & 4) ? mb  : ma;
    return (wr & 1) ? mf.y : mf.x;
  };

  // one step: pure registers + DPP; z-neighbors are adjacent pairs in-thread.
  // p' = 2c - prev + c2*(up+dn+l+r - 4c)
  auto do_step = [&](v2f (&cur)[NPRW], v2f (&nxt)[NPRW], int tau, int t0) {
    #pragma unroll
    for (int p = 0; p < NPRW; ++p) {
      const float cx = cur[p].x, cy = cur[p].y;
      const float upx = (p == 0)        ? 0.0f : cur[p - 1].y;
      const float dny = (p == NPRW - 1) ? 0.0f : cur[p + 1].x;
      v2f ud, lr;
      ud.x = upx + cy;
      ud.y = cx + dny;
      lr.x = nbr_left(cx) + nbr_right(cx);
      lr.y = nbr_left(cy) + nbr_right(cy);
      const v2f sum = ud + lr;
      const v2f s4 = __builtin_elementwise_fma((v2f)(-4.0f), cur[p], sum);
      const v2f tt = __builtin_elementwise_fma((v2f)(2.0f),  cur[p], -nxt[p]);
      nxt[p] = __builtin_elementwise_fma(c22[p], s4, tt);
    }
    if (hasSrc) {                        // wave-uniform; ~8/384 waves pay
      const float av = amp[tau];
      #pragma unroll
      for (int p = 0; p < NPRW; ++p) {
        if (srcLane && wz == 2 * p)     nxt[p].x += av;
        if (srcLane && wz == 2 * p + 1) nxt[p].y += av;
      }
    }
    // receiver stores: owner thread has the value in registers
    const int t = t0 + tau;
    if (e0 & 0x8000u)
      out[(s * NT + t) * NRECS + (e0 & 127u)] = selRow(nxt, (e0 >> 8) & 31);
    if (e1 & 0x8000u)
      out[(s * NT + t) * NRECS + (e1 & 127u)] = selRow(nxt, (e1 >> 8) & 31);
    if (hasOvf) {                        // >2 recs on one thread (rare)
      #pragma unroll
      for (int wd = 0; wd < 4; ++wd) {
        unsigned m = ov[wd];
        while (m) {
          const int b = __builtin_ctz(m); m &= m - 1;
          const int r = wd * 32 + b;
          const int wr = rec_z[s * NRECS + r] - tz * TZ + K;
          out[(s * NT + t) * NRECS + r] = selRow(nxt, wr);
        }
      }
    }
  };

  #pragma unroll 1
  for (int ph = 0; ph < NPH; ++ph) {
    const int t0 = ph * K;

    if (hasSrc) {                        // wavelet only for source waves
      const float4 v  = *(const float4*)(xwav + s * NT + t0);
      const float4 u4 = *(const float4*)(xwav + s * NT + t0 + 4);
      amp[0] = v.x * DTf * DTf;  amp[1] = v.y * DTf * DTf;
      amp[2] = v.z * DTf * DTf;  amp[3] = v.w * DTf * DTf;
      amp[4] = u4.x * DTf * DTf; amp[5] = u4.y * DTf * DTf;
      amp[6] = u4.z * DTf * DTf; amp[7] = u4.w * DTf * DTf;
    }

    if (ph > 0) {
      // fused poll+reload on self-tagged data words (R6-proven protocol):
      // tag match certifies the producer's phase-(ph-1) writeback AND (by
      // its program order: loads consumed before stores issue) its prior
      // reload of the buffer I overwrite later -> data-dep and anti-dep
      // both covered; 3-tag cycle prevents ABA. Single LLC round trip.
      const ull* gR = (ph & 1) ? gA : gB;          // buf[(ph-1)&1]
      const unsigned tg = tag_of(ph - 1);
      unsigned need = okBits & ~keepM;
      while (need) {
        ull tv[EXTZ];
        #pragma unroll
        for (int i = 0; i < EXTZ; ++i)
          if (need & (1u << i)) tv[i] = pload(gR + off0 + i * NX);
        #pragma unroll
        for (int i = 0; i < EXTZ; ++i)
          if ((need & (1u << i)) &&
              ((((unsigned)(tv[i] >> 32)) & 3u) == tg)) {
            const float cv = w_cur(tv[i]), pv = w_prev(tv[i]);
            if (i & 1) { a2[i >> 1].y = cv; b2[i >> 1].y = pv; }
            else       { a2[i >> 1].x = cv; b2[i >> 1].x = pv; }
            need &= ~(1u << i);
          }
        if (need) __builtin_amdgcn_s_sleep(1);
      }
      // out-of-domain rows: reset eroded garbage to 0 (zero-pad semantics)
      #pragma unroll
      for (int i = 0; i < EXTZ; ++i)
        if (!(okBits & (1u << i))) {
          if (i & 1) { a2[i >> 1].y = 0.0f; b2[i >> 1].y = 0.0f; }
          else       { a2[i >> 1].x = 0.0f; b2[i >> 1].x = 0.0f; }
        }
    }

    // 8 pure-register steps (no LDS, no barriers anywhere in the kernel)
    #pragma unroll
    for (int h = 0; h < K / 2; ++h) {
      do_step(a2, b2, 2 * h,     t0);
      do_step(b2, a2, 2 * h + 1, t0);
    }
    // after 8 steps: a2 = p(t0+8), b2 = p(t0+7); exact on interior 16x48

    if (ph != NPH - 1 && wbLane) {
      // tagged writeback IS the handshake (no drain, no flags)
      ull* gW = (ph & 1) ? gB : gA;                // buf[ph&1]
      const unsigned tgw = tag_of(ph);
      #pragma unroll
      for (int k = 0; k < TZ; ++k) {
        const int i = K + k;                       // window rows 8..23
        const float cv = (i & 1) ? a2[i >> 1].y : a2[i >> 1].x;
        const float pv = (i & 1) ? b2[i >> 1].y : b2[i >> 1].x;
        pstore(gW + off0 + i * NX, pack_w(cv, pv, tgw));
      }
    }
  }
}

extern "C" void kernel_launch(void* const* d_in, const int* in_sizes, int n_in,
                              void* d_out, int out_size, void* d_ws, size_t ws_size,
                              hipStream_t stream) {
  const float* x     = (const float*)d_in[0];
  const float* vp    = (const float*)d_in[1];
  const int*   src_z = (const int*)d_in[2];
  const int*   src_x = (const int*)d_in[3];
  const int*   rec_z = (const int*)d_in[4];
  const int*   rec_x = (const int*)d_in[5];
  float* out = (float*)d_out;

  const size_t F = (size_t)NSHOTS * NZ * NX;
  ull* gA = (ull*)d_ws;                 // tagged (cur,prev), F words
  ull* gB = gA + F;                     // F words

  // zero both buffers: tag bits 0 never match any valid tag (1..3)
  hipMemsetAsync(gA, 0, 2 * F * sizeof(ull), stream);

  wave_pk<<<dim3(NTILES), dim3(64), 0, stream>>>(
      gA, gB, vp, x, src_z, src_x, rec_z, rec_x, out);
}

// Round 12
// 320.243 us; speedup vs baseline: 1.9752x; 1.9752x over previous
//
#include <hip/hip_runtime.h>

#define NSHOTS 4
#define NT     512
#define NZ     256
#define NX     256
#define NRECS  128

static constexpr float DTf    = 0.001f;
static constexpr float INVDH2 = 1.0f / (10.0f * 10.0f);

#define KSTEPS 16                 // fused steps per phase
#define TILE   32                 // interior tile edge
#define RPT    8                  // ext rows per thread (4 float2 pairs)
#define NPAIRS 4                  // RPT/2
#define NWAVES 8
#define BLOCK  512
#define NWG    (NSHOTS * 64)      // 256 WGs, one per CU (co-resident)
#define NPHASE (NT / KSTEPS)      // 32

typedef float v2f __attribute__((ext_vector_type(2)));
typedef unsigned long long ull;

// lane i <- lane i-1 (left x-neighbor); OOB lane 0 reads 0 (bound_ctrl=1)
__device__ __forceinline__ float nbr_left(float v) {
  return __int_as_float(__builtin_amdgcn_update_dpp(
      0, __float_as_int(v), 0x138 /*WAVE_SHR1*/, 0xf, 0xf, true));
}
// lane i <- lane i+1 (right x-neighbor); OOB lane 63 reads 0
__device__ __forceinline__ float nbr_right(float v) {
  return __int_as_float(__builtin_amdgcn_update_dpp(
      0, __float_as_int(v), 0x130 /*WAVE_SHL1*/, 0xf, 0xf, true));
}

// LLC-coherent (cross-XCD) 8B access: agent-scope relaxed -> sc0 sc1.
__device__ __forceinline__ ull pload(const ull* p) {
  return __hip_atomic_load(p, __ATOMIC_RELAXED, __HIP_MEMORY_SCOPE_AGENT);
}
__device__ __forceinline__ void pstore(ull* p, ull v) {
  __hip_atomic_store(p, v, __ATOMIC_RELAXED, __HIP_MEMORY_SCOPE_AGENT);
}

// pack (cur, prev) into one self-tagged 8B word: low 2 bits of prev's
// mantissa carry the phase tag (<= 3 ulp perturbation of halo prev only)
__device__ __forceinline__ ull pack_w(float cur, float prev, unsigned tg) {
  const unsigned hi = (__float_as_uint(prev) & ~3u) | tg;
  return ((ull)hi << 32) | (ull)__float_as_uint(cur);
}
__device__ __forceinline__ float w_cur(ull w) {
  return __uint_as_float((unsigned)w);
}
__device__ __forceinline__ float w_prev(ull w) {
  return __uint_as_float(((unsigned)(w >> 32)) & ~3u);
}
// per-buffer tag cycles 1,2,3 (phase q uses buffer q&1): never 0 (= memset)
__device__ __forceinline__ unsigned tag_of(int q) {
  return ((unsigned)(q >> 1) % 3u) + 1u;
}

__global__ __launch_bounds__(BLOCK, 4) void wave_pk(
    ull* __restrict__ gA, ull* __restrict__ gB,         // tagged (cur,prev) buffers
    const float* __restrict__ vp, const float* __restrict__ xwav,
    const int* __restrict__ src_z, const int* __restrict__ src_x,
    const int* __restrict__ rec_z, const int* __restrict__ rec_x,
    float* __restrict__ out)                            // [NSHOTS*NT*NRECS]
{
  const int bid  = blockIdx.x;
  const int s    = bid >> 6;
  const int tz   = (bid >> 3) & 7;
  const int tx   = bid & 7;
  const int tid  = threadIdx.x;
  const int w    = tid >> 6;
  const int lane = tid & 63;

  const int gz0 = tz * TILE - KSTEPS;
  const int gx0 = tx * TILE - KSTEPS;
  const int gx  = gx0 + lane;
  const int zb  = w * RPT;

  __shared__ float haloTop[2][NWAVES][64];
  __shared__ float haloBot[2][NWAVES][64];
  __shared__ int   lzA[NRECS], lxA[NRECS];

  // receiver table -> LDS
  if (tid < NRECS) {
    lzA[tid] = rec_z[s * NRECS + tid] - tz * TILE;
    lxA[tid] = rec_x[s * NRECS + tid] - tx * TILE;
  }
  __syncthreads();

  const bool wbRow = (w >= 2 && w < 6) && (lane >= KSTEPS && lane < KSTEPS + TILE);

  // receiver ownership: owner thread holds the cell in registers.
  // 2 packed fast slots {valid<<15 | row<<8 | recIdx} + overflow bitmask.
  unsigned e0 = 0, e1 = 0, ov[4] = {0, 0, 0, 0};
  if (wbRow) {
    int cnt = 0;
    #pragma unroll 1
    for (int r = 0; r < NRECS; ++r) {
      const int lz = lzA[r], lx = lxA[r];
      if ((unsigned)lz < (unsigned)TILE && (unsigned)lx < (unsigned)TILE) {
        const int ez = lz + KSTEPS;                 // ext row 16..47
        if ((ez >> 3) == w && lx + KSTEPS == lane) {
          const unsigned e = 0x8000u | ((unsigned)(ez & 7) << 8) | (unsigned)r;
          if (cnt == 0) e0 = e;
          else if (cnt == 1) e1 = e;
          else ov[r >> 5] |= 1u << (r & 31);
          ++cnt;
        }
      }
    }
  }
  const bool hasOvf = (ov[0] | ov[1] | ov[2] | ov[3]) != 0;

  // source mask, packed per row-pair (uniform FMA pass, as R6 — keeps all
  // waves' instruction streams identical, which the lock-step barrier likes)
  const int slz = src_z[s] - gz0;
  const int slx = src_x[s] - gx0;
  const bool srcMine = (slx == lane) && ((unsigned)(slz - zb) < (unsigned)RPT);
  const int  srcI = slz - zb;
  v2f srcM2[NPAIRS];
  #pragma unroll
  for (int p = 0; p < NPAIRS; ++p) {
    srcM2[p].x = (srcMine && srcI == 2 * p)     ? 1.0f : 0.0f;
    srcM2[p].y = (srcMine && srcI == 2 * p + 1) ? 1.0f : 0.0f;
  }

  // phase-invariant per-row addresses/validity; c2 and d2=2-4c2 packed
  const bool xok = (unsigned)gx < (unsigned)NX;
  int   offRow[RPT];
  bool  okRow[RPT];
  v2f a2[NPAIRS], b2[NPAIRS], c22[NPAIRS], d22[NPAIRS];
  unsigned okMask = 0;
  #pragma unroll
  for (int p = 0; p < NPAIRS; ++p) {
    #pragma unroll
    for (int h = 0; h < 2; ++h) {
      const int i  = 2 * p + h;
      const int gz = gz0 + zb + i;
      const bool ok = xok && ((unsigned)gz < (unsigned)NZ);
      okRow[i]  = ok;
      if (ok) okMask |= 1u << i;
      offRow[i] = ok ? ((s * NZ + gz) * NX + gx) : 0;
      float v = ok ? vp[gz * NX + gx] : 0.0f;
      v *= DTf;
      const float c2 = v * v * INVDH2;
      if (h == 0) { c22[p].x = c2; d22[p].x = 2.0f - 4.0f * c2; }
      else        { c22[p].y = c2; d22[p].y = 2.0f - 4.0f * c2; }
    }
    a2[p] = (v2f)(0.0f); b2[p] = (v2f)(0.0f);
  }

  // value of my-wave ext row (0..7) from nxt pairs
  auto selRow = [](const v2f (&n)[NPAIRS], int row) -> float {
    const v2f pA = (row & 2) ? n[1] : n[0];
    const v2f pB = (row & 2) ? n[3] : n[2];
    const v2f pp = (row & 4) ? pB : pA;
    return (row & 1) ? pp.y : pp.x;
  };

  #pragma unroll 1
  for (int ph = 0; ph < NPHASE; ++ph) {
    const int t0 = ph * KSTEPS;

    // 16 source amps via 4 vector loads (uniform, broadcast-friendly)
    float amp[KSTEPS];
    {
      const float4* xw4 = (const float4*)(xwav + s * NT + t0);
      #pragma unroll
      for (int q = 0; q < KSTEPS / 4; ++q) {
        const float4 v = xw4[q];
        amp[4 * q + 0] = (v.x * DTf) * DTf;
        amp[4 * q + 1] = (v.y * DTf) * DTf;
        amp[4 * q + 2] = (v.z * DTf) * DTf;
        amp[4 * q + 3] = (v.w * DTf) * DTf;
      }
    }

    if (ph > 0 && !wbRow) {
      // fused poll+reload on self-tagged data words (R6-proven): tag match
      // certifies producer's phase-(ph-1) writeback AND (program order) its
      // prior reload of the buffer I overwrite this phase -> covers both
      // data-dep and anti-dep. No flags, no drains, no broadcast barrier.
      const ull* gR = (ph & 1) ? gA : gB;   // buffer[(ph-1)&1]
      const unsigned tg = tag_of(ph - 1);
      ull vw[RPT];
      unsigned need = okMask;
      while (need) {
        ull t[RPT];
        #pragma unroll
        for (int i = 0; i < RPT; ++i)
          if (need & (1u << i)) t[i] = pload(gR + offRow[i]);
        #pragma unroll
        for (int i = 0; i < RPT; ++i)
          if ((need & (1u << i)) && (((unsigned)(t[i] >> 32)) & 3u) == tg) {
            vw[i] = t[i];
            need &= ~(1u << i);
          }
        if (need) __builtin_amdgcn_s_sleep(1);
      }
      #pragma unroll
      for (int i = 0; i < RPT; ++i) {
        const float cv = okRow[i] ? w_cur(vw[i])  : 0.0f;
        const float pv = okRow[i] ? w_prev(vw[i]) : 0.0f;
        if (i & 1) { a2[i >> 1].y = cv; b2[i >> 1].y = pv; }
        else       { a2[i >> 1].x = cv; b2[i >> 1].x = pv; }
      }
    }

    // one step, row-pair packed: p' = d2*c + c2*sum - prev (+ src)
    // receiver values leave via direct global stores from the owner thread
    // (fire-and-forget; no LDS staging, no extra barrier).
    auto do_step = [&](v2f (&cur)[NPAIRS], v2f (&nxt)[NPAIRS], int tau) {
      const int pb = tau & 1;
      haloTop[pb][w][lane] = cur[0].x;
      haloBot[pb][w][lane] = cur[NPAIRS - 1].y;
      __syncthreads();
      const float up0 = (w > 0)          ? haloBot[pb][w - 1][lane] : 0.0f;
      const float dn7 = (w < NWAVES - 1) ? haloTop[pb][w + 1][lane] : 0.0f;
      const v2f av = { amp[tau], amp[tau] };
      #pragma unroll
      for (int p = 0; p < NPAIRS; ++p) {
        const float cx = cur[p].x, cy = cur[p].y;
        const float upx = (p == 0)          ? up0 : cur[p - 1].y;
        const float dny = (p == NPAIRS - 1) ? dn7 : cur[p + 1].x;
        v2f ud, lr;
        ud.x = upx + cy;
        ud.y = cx + dny;
        lr.x = nbr_left(cx) + nbr_right(cx);
        lr.y = nbr_left(cy) + nbr_right(cy);
        const v2f sum = ud + lr;
        v2f t = __builtin_elementwise_fma(c22[p], sum, -nxt[p]);
        t = __builtin_elementwise_fma(d22[p], cur[p], t);
        t = __builtin_elementwise_fma(srcM2[p], av, t);
        nxt[p] = t;
      }
      // out[t0+tau] = state after this step (matches reference p_next read)
      const int t = t0 + tau;
      if (e0 & 0x8000u)
        out[(s * NT + t) * NRECS + (e0 & 127u)] = selRow(nxt, (e0 >> 8) & 7);
      if (e1 & 0x8000u)
        out[(s * NT + t) * NRECS + (e1 & 127u)] = selRow(nxt, (e1 >> 8) & 7);
      if (hasOvf) {                      // >2 recs on one thread (rare)
        #pragma unroll
        for (int wd = 0; wd < 4; ++wd) {
          unsigned m = ov[wd];
          while (m) {
            const int b = __builtin_ctz(m); m &= m - 1;
            const int r = wd * 32 + b;
            out[(s * NT + t) * NRECS + r] = selRow(nxt, (lzA[r] + KSTEPS) & 7);
          }
        }
      }
    };

    #pragma unroll
    for (int h = 0; h < KSTEPS / 2; ++h) {
      do_step(a2, b2, 2 * h);
      do_step(b2, a2, 2 * h + 1);
    }

    if (ph != NPHASE - 1 && wbRow) {
      // tagged writeback IS the inter-tile handshake (no drain, no flag).
      // No end-of-phase barrier needed: slot-0 WAR for next phase's step 0
      // is covered by step-15's collective barrier (all slot-0 reads were
      // pre-barrier-15), and step-0's own barrier orders the new writes.
      ull* gW = (ph & 1) ? gB : gA;      // buffer[ph&1]
      const unsigned tgw = tag_of(ph);
      #pragma unroll
      for (int p = 0; p < NPAIRS; ++p) {
        pstore(gW + offRow[2 * p],     pack_w(a2[p].x, b2[p].x, tgw));
        pstore(gW + offRow[2 * p + 1], pack_w(a2[p].y, b2[p].y, tgw));
      }
    }
  }
}

extern "C" void kernel_launch(void* const* d_in, const int* in_sizes, int n_in,
                              void* d_out, int out_size, void* d_ws, size_t ws_size,
                              hipStream_t stream) {
  const float* x     = (const float*)d_in[0];
  const float* vp    = (const float*)d_in[1];
  const int*   src_z = (const int*)d_in[2];
  const int*   src_x = (const int*)d_in[3];
  const int*   rec_z = (const int*)d_in[4];
  const int*   rec_x = (const int*)d_in[5];
  float* out = (float*)d_out;

  const size_t F = (size_t)NSHOTS * NZ * NX;
  ull* gA = (ull*)d_ws;                 // tagged (cur,prev), F words
  ull* gB = gA + F;                     // F words

  // zero both buffers: tag bits 0 never match any valid tag (1..3)
  hipMemsetAsync(gA, 0, 2 * F * sizeof(ull), stream);

  wave_pk<<<dim3(NWG), dim3(BLOCK), 0, stream>>>(
      gA, gB, vp, x, src_z, src_x, rec_z, rec_x, out);
}